// Round 4
// baseline (598.964 us; speedup 1.0000x reference)
//
#include <hip/hip_runtime.h>
#include <hip/hip_bf16.h>
#include <cstdint>

// Problem: B=32, S=2048, H=1024
//   c[b,o]   = hidden[b,:].Wh[o,:] + bias[o]        (Wh = W_attn[:, :H])
//   e[b,s,o] = enc[b,s,:].We[o,:]                   (We = W_attn[:, H:])
//   logit[b,s] = sum_o tanh(e + c) * v[o];  out = softmax over s
//
// R4: fused kernel, occupancy-fixed. 1024 blocks x 1024 threads, BM=64,
// wave tile 64x64 -> acc = 64 regs/lane; __launch_bounds__(1024) caps the
// unified VGPR+AGPR budget at 128 -> 4 waves/SIMD (vs R3's 2). B frags come
// fragment-major from L2 with a one-step lookahead ring (covered at 4 w/SIMD);
// enc fp32 loads for phase p+1 issued a full phase (~1200 cyc) early.
// Block-level LDS reduction -> single logits array (npart=1).

#define HDIM 1024
#define SDIM 2048
#define MTOT 65536

typedef __attribute__((ext_vector_type(8))) short short8;   // 8 bf16
typedef __attribute__((ext_vector_type(4))) float floatx4;  // MFMA acc

__device__ __forceinline__ unsigned short f2bf(float f) {
    unsigned int u = __float_as_uint(f);
    u += 0x7fffu + ((u >> 16) & 1u);   // RNE
    return (unsigned short)(u >> 16);
}
__device__ __forceinline__ unsigned int pack2(float a, float b) {
    return (unsigned int)f2bf(a) | ((unsigned int)f2bf(b) << 16);
}
__device__ __forceinline__ float fast_tanh(float x) {
    float e2 = __expf(2.f * x);
    return 1.f - 2.f * __builtin_amdgcn_rcpf(e2 + 1.f);
}

// ---- convert We (W_attn[:, H:2H], row stride 2H) into fragment-major bf16 ----
// tile (jt in [0,64), kc in [0,32)): 16 n-rows x 32 k; ushort base = (jt*32+kc)*512.
// lane l = g*16+lc holds B[n=jt*16+lc][k=kc*32+g*8+jj], jj in [0,8) at base+l*8+jj.
__global__ __launch_bounds__(256) void convert_W2(const float* __restrict__ W,
                                                  unsigned short* __restrict__ Wbf2) {
    int T = blockIdx.x * 256 + threadIdx.x;   // [0, 131072): (n, k8)
    int n  = T >> 7;
    int k8 = T & 127;
    int k  = k8 * 8;
    const float4* src = (const float4*)(W + (size_t)n * 2048 + 1024 + k);
    float4 f0 = src[0], f1 = src[1];
    int jt = n >> 4, lc = n & 15, kc = k8 >> 2, g = k8 & 3;
    uint4 u;
    u.x = pack2(f0.x, f0.y); u.y = pack2(f0.z, f0.w);
    u.z = pack2(f1.x, f1.y); u.w = pack2(f1.z, f1.w);
    *(uint4*)(Wbf2 + (size_t)(jt * 32 + kc) * 512 + (g * 16 + lc) * 8) = u;
}

// ---- c[b,o] = hidden[b,:].Wh[o,:] + bias[o]; one block per o ----
__global__ __launch_bounds__(256) void calc_c(const float* __restrict__ hid,
                                              const float* __restrict__ W,
                                              const float* __restrict__ bias,
                                              float* __restrict__ c) {
    __shared__ float red[4][32];
    const int o = blockIdx.x;
    const int wave = threadIdx.x >> 6, lane = threadIdx.x & 63;
    const int k = wave * 256 + lane * 4;
    const float4 wv = *(const float4*)(W + (size_t)o * 2048 + k);
    float acc[32];
#pragma unroll
    for (int b = 0; b < 32; ++b) {
        const float4 h = *(const float4*)(hid + b * HDIM + k);
        acc[b] = wv.x * h.x + wv.y * h.y + wv.z * h.z + wv.w * h.w;
    }
#pragma unroll
    for (int b = 0; b < 32; ++b) {
        float x = acc[b];
        for (int off = 32; off; off >>= 1) x += __shfl_xor(x, off);
        if (lane == 0) red[wave][b] = x;
    }
    __syncthreads();
    if (threadIdx.x < 32) {
        int b = threadIdx.x;
        c[b * HDIM + o] = red[0][b] + red[1][b] + red[2][b] + red[3][b] + bias[o];
    }
}

// ---- fused GEMM + tanh + v-dot ----
#define PHN 8     // K phases
#define PHK 128   // K per phase

__global__ __launch_bounds__(1024) void attn_fused(const float* __restrict__ enc,
                                                   const unsigned short* __restrict__ Wbf2,
                                                   const float* __restrict__ c,
                                                   const float* __restrict__ v,
                                                   float* __restrict__ logits) {
    // slab: 64 rows x 128 k bf16 (16 chunks of 8 bf16 per row).
    // chunk kk of row r stored at slot kk ^ (r&7): frag reads AND staged writes
    // both spread evenly over the 8 bank-groups (0 conflicts).
    __shared__ __align__(16) unsigned short slab[2][64 * 128];   // 2 x 16 KB
    __shared__ float redbuf[16][64];                             // 4 KB

    const int tid  = threadIdx.x;
    const int lane = tid & 63;
    const int wave = tid >> 6;    // 0..15
    const int grp  = lane >> 4;   // 0..3
    const int lc   = lane & 15;

    const int m0 = blockIdx.x * 64;
    const int b  = m0 >> 11;      // batch (64-row blocks never straddle b)

    // staging: thread t -> row r = t>>4, LDS slot C = t&15, global chunk kk = C^(r&7)
    const int s_r  = tid >> 4;
    const int s_C  = tid & 15;
    const int s_kk = s_C ^ (s_r & 7);
    const float* gA = enc + (size_t)(m0 + s_r) * HDIM + s_kk * 8;

    floatx4 acc[4][4];
#pragma unroll
    for (int i = 0; i < 4; ++i)
#pragma unroll
        for (int j = 0; j < 4; ++j) acc[i][j] = (floatx4){0.f, 0.f, 0.f, 0.f};

    const short8* Bfr = (const short8*)Wbf2;   // 16B-granular indexing

    // prologue: stage phase 0 into buf 0
    {
        float4 la0 = *(const float4*)(gA);
        float4 la1 = *(const float4*)(gA + 4);
        uint4 u;
        u.x = pack2(la0.x, la0.y); u.y = pack2(la0.z, la0.w);
        u.z = pack2(la1.x, la1.y); u.w = pack2(la1.z, la1.w);
        *(uint4*)(&slab[0][s_r * 128 + s_C * 8]) = u;
    }

    // B lookahead ring (one kc-step ahead; 4 waves/SIMD cover the L2 latency)
    short8 bf[4], bn[4];
#pragma unroll
    for (int j = 0; j < 4; ++j)
        bf[j] = Bfr[(size_t)((wave * 4 + j) * 32 + 0) * 64 + lane];

#pragma unroll 1
    for (int p = 0; p < PHN; ++p) {
        __syncthreads();   // slab[p&1] fully written, previous buffer free

        float4 la0, la1;
        if (p < PHN - 1) {   // issue next-phase HBM loads a full phase early
            la0 = *(const float4*)(gA + (p + 1) * PHK);
            la1 = *(const float4*)(gA + (p + 1) * PHK + 4);
        }

        const unsigned short* sl = slab[p & 1];
#pragma unroll
        for (int kc = 0; kc < 4; ++kc) {
            short8 af[4];
#pragma unroll
            for (int i = 0; i < 4; ++i)
                af[i] = *(const short8*)(sl + (i * 16 + lc) * 128 +
                                         (((kc * 4 + grp) ^ (lc & 7)) * 8));
            // prefetch B for next kc-step (crosses into next phase at kc==3)
            {
                const int kn = (kc < 3) ? (p * 4 + kc + 1)
                                        : ((p < PHN - 1) ? (p + 1) * 4 : 31);
#pragma unroll
                for (int j = 0; j < 4; ++j)
                    bn[j] = Bfr[(size_t)((wave * 4 + j) * 32 + kn) * 64 + lane];
            }
#pragma unroll
            for (int i = 0; i < 4; ++i)
#pragma unroll
                for (int j = 0; j < 4; ++j)
                    acc[i][j] = __builtin_amdgcn_mfma_f32_16x16x32_bf16(
                        af[i], bf[j], acc[i][j], 0, 0, 0);
#pragma unroll
            for (int j = 0; j < 4; ++j) bf[j] = bn[j];
        }

        if (p < PHN - 1) {   // pack + write next phase's slab
            uint4 u;
            u.x = pack2(la0.x, la0.y); u.y = pack2(la0.z, la0.w);
            u.z = pack2(la1.x, la1.y); u.w = pack2(la1.z, la1.w);
            *(uint4*)(&slab[(p + 1) & 1][s_r * 128 + s_C * 8]) = u;
        }
    }

    // epilogue: rowsum over this wave's 64 cols, tanh(e + c) * v
    float rowsum[4][4];
#pragma unroll
    for (int i = 0; i < 4; ++i)
#pragma unroll
        for (int r = 0; r < 4; ++r) rowsum[i][r] = 0.f;

#pragma unroll
    for (int j = 0; j < 4; ++j) {
        const int n  = wave * 64 + j * 16 + lc;
        const float vn = v[n];
        const float cv = c[b * HDIM + n];
#pragma unroll
        for (int i = 0; i < 4; ++i)
#pragma unroll
            for (int r = 0; r < 4; ++r)
                rowsum[i][r] = fmaf(fast_tanh(acc[i][j][r] + cv), vn, rowsum[i][r]);
    }

#pragma unroll
    for (int i = 0; i < 4; ++i)
#pragma unroll
        for (int r = 0; r < 4; ++r) {
            float x = rowsum[i][r];
            x += __shfl_xor(x, 8);
            x += __shfl_xor(x, 4);
            x += __shfl_xor(x, 2);
            x += __shfl_xor(x, 1);
            if (lc == 0) redbuf[wave][i * 16 + grp * 4 + r] = x;
        }
    __syncthreads();
    if (tid < 64) {
        float s = 0.f;
#pragma unroll
        for (int w = 0; w < 16; ++w) s += redbuf[w][tid];
        logits[m0 + tid] = s;
    }
}

// ---- softmax over S=2048 per batch row ----
__global__ __launch_bounds__(256) void softmax_k(const float* __restrict__ logits,
                                                 float* __restrict__ out) {
    __shared__ float wred[4];
    const int bb = blockIdx.x;
    const int tid = threadIdx.x;
    const int wave = tid >> 6, lane = tid & 63;
    const float* lg = logits + (size_t)bb * SDIM;

    float vals[8];
    float lmax = -INFINITY;
#pragma unroll
    for (int q = 0; q < 8; ++q) {
        vals[q] = lg[q * 256 + tid];
        lmax = fmaxf(lmax, vals[q]);
    }
    for (int off = 32; off; off >>= 1) lmax = fmaxf(lmax, __shfl_xor(lmax, off));
    if (lane == 0) wred[wave] = lmax;
    __syncthreads();
    lmax = fmaxf(fmaxf(wred[0], wred[1]), fmaxf(wred[2], wred[3]));
    __syncthreads();

    float e[8];
    float s = 0.f;
#pragma unroll
    for (int q = 0; q < 8; ++q) {
        e[q] = __expf(vals[q] - lmax);
        s += e[q];
    }
    for (int off = 32; off; off >>= 1) s += __shfl_xor(s, off);
    if (lane == 0) wred[wave] = s;
    __syncthreads();
    s = wred[0] + wred[1] + wred[2] + wred[3];
    const float inv = 1.f / s;
#pragma unroll
    for (int q = 0; q < 8; ++q)
        out[(size_t)bb * SDIM + q * 256 + tid] = e[q] * inv;
}

extern "C" void kernel_launch(void* const* d_in, const int* in_sizes, int n_in,
                              void* d_out, int out_size, void* d_ws, size_t ws_size,
                              hipStream_t stream) {
    const float* hidden = (const float*)d_in[0];   // (1, 32, 1024)
    const float* enc    = (const float*)d_in[1];   // (32, 2048, 1024)
    const float* W      = (const float*)d_in[2];   // (1024, 2048)
    const float* battn  = (const float*)d_in[3];   // (1024,)
    const float* v      = (const float*)d_in[4];   // (1024,)
    float* out = (float*)d_out;                    // (32, 2048)

    char* ws = (char*)d_ws;
    float* c             = (float*)ws;                           // 128 KB
    float* logits        = (float*)(ws + (128 << 10));           // 256 KB
    unsigned short* Wbf2 = (unsigned short*)(ws + (384 << 10));  // 2 MB

    hipLaunchKernelGGL(convert_W2, dim3(512),  dim3(256),  0, stream, W, Wbf2);
    hipLaunchKernelGGL(calc_c,     dim3(1024), dim3(256),  0, stream, hidden, W, battn, c);
    hipLaunchKernelGGL(attn_fused, dim3(1024), dim3(1024), 0, stream, enc, Wbf2, c, v, logits);
    hipLaunchKernelGGL(softmax_k,  dim3(32),   dim3(256),  0, stream, logits, out);
}